// Round 2
// baseline (320.186 us; speedup 1.0000x reference)
//
#include <hip/hip_runtime.h>
#include <math.h>

#define Bn 32
#define Qn 300
#define Tn 64
#define Cn 2
#define Mcols Qn   /* LSA columns (queries) */
#define Nrows Tn   /* LSA rows (targets)   */

#define CLS_SCALE_F 0.1f
#define BBOX_SCALE_D 5.0
#define GIOU_SCALE_D 2.0

// ---------------------------------------------------------------------------
// Fused kernel: build 64x300 cost tile in LDS, then Jonker-Volgenant LSA.
// One 64-lane wave per batch. Mirrors reference _lsa exactly (f64 duals,
// (cost-u)-v evaluation order, first-index argmin tie-break).
// All loops are bounded (defensive: no input can hang the device).
// ---------------------------------------------------------------------------
__global__ __launch_bounds__(64) void lsa_fused_kernel(
    const float* __restrict__ logits,        // [B][Q][C]
    const float* __restrict__ pred_bbox,     // [B][Q][4] cxcywh
    const float* __restrict__ target_bbox,   // [B][T][4] cxcywh
    const int*   __restrict__ target_labels, // [B][T]
    int* __restrict__ src)                   // [B][T] -> matched query
{
    const int b   = blockIdx.x;
    const int tid = threadIdx.x;

    __shared__ float  cst[Nrows * Mcols];     // 76800 B
    __shared__ double u[Nrows + 1];
    __shared__ double v[Mcols + 1];
    __shared__ double minv[Mcols + 1];
    __shared__ int    p[Mcols + 1];
    __shared__ int    way[Mcols + 1];
    __shared__ int    used[Mcols + 1];
    __shared__ float  tb4[Tn * 4];
    __shared__ int    tlab[Tn];

    // ---- stage targets ----
    for (int k = tid; k < Tn * 4; k += 64) tb4[k] = target_bbox[b * Tn * 4 + k];
    for (int k = tid; k < Tn; k += 64)     tlab[k] = target_labels[b * Tn + k];
    __syncthreads();

    // ---- build cost tile: lane owns query q, loops over all 64 targets ----
    for (int qt = 0; qt < (Mcols + 63) / 64; ++qt) {
        int q = qt * 64 + tid;
        if (q < Qn) {
            float l0 = logits[(b * Qn + q) * Cn + 0];
            float l1 = logits[(b * Qn + q) * Cn + 1];
            float mx = fmaxf(l0, l1);
            float e0 = expf(l0 - mx), e1 = expf(l1 - mx);
            float den = e0 + e1;
            float pce0 = e0 / den, pce1 = e1 / den;

            const float* pb = pred_bbox + (b * Qn + q) * 4;
            float pcx = pb[0], pcy = pb[1], pw = pb[2], ph = pb[3];
            float p0 = pcx - 0.5f * pw, p1 = pcy - 0.5f * ph;
            float p2 = pcx + 0.5f * pw, p3 = pcy + 0.5f * ph;
            float area1 = (p2 - p0) * (p3 - p1);

            for (int t = 0; t < Tn; ++t) {
                float tcx = tb4[t * 4 + 0], tcy = tb4[t * 4 + 1];
                float tw  = tb4[t * 4 + 2], th  = tb4[t * 4 + 3];
                float cost_bbox = fabsf(pcx - tcx) + fabsf(pcy - tcy) +
                                  fabsf(pw - tw) + fabsf(ph - th);
                float cost_class = (tlab[t] == 0) ? -pce0 : -pce1;

                float t0 = tcx - 0.5f * tw, t1 = tcy - 0.5f * th;
                float t2 = tcx + 0.5f * tw, t3 = tcy + 0.5f * th;
                float area2 = (t2 - t0) * (t3 - t1);
                float ltx = fmaxf(p0, t0), lty = fmaxf(p1, t1);
                float rbx = fminf(p2, t2), rby = fminf(p3, t3);
                float iw = fmaxf(rbx - ltx, 0.0f), ih = fmaxf(rby - lty, 0.0f);
                float inter = iw * ih;
                float uni   = area1 + area2 - inter;
                float iou   = inter / uni;
                float ex0 = fminf(p0, t0), ey0 = fminf(p1, t1);
                float ex1 = fmaxf(p2, t2), ey1 = fmaxf(p3, t3);
                float ew = fmaxf(ex1 - ex0, 0.0f), eh = fmaxf(ey1 - ey0, 0.0f);
                float enc = ew * eh;
                float giou = iou - (enc - uni) / enc;

                cst[t * Mcols + q] = cost_bbox + cost_class - giou;
            }
        }
    }

    // ---- init LSA state ----
    for (int j = tid; j <= Mcols; j += 64) { v[j] = 0.0; p[j] = 0; way[j] = 0; }
    for (int i = tid; i <= Nrows; i += 64) u[i] = 0.0;
    __syncthreads();

    for (int i = 1; i <= Nrows; ++i) {
        if (tid == 0) p[0] = i;
        for (int j = tid; j <= Mcols; j += 64) { minv[j] = INFINITY; used[j] = 0; }
        __syncthreads();

        int j0 = 0;
        // Dijkstra over columns; terminates at a free column. Bounded cap
        // (never reached in correct operation) guards against device hangs.
        for (int step = 0; step <= Mcols + 1; ++step) {
            if (tid == 0) used[j0] = 1;
            __syncthreads();
            int i0 = p[j0];
            double ui0 = u[i0];
            const float* crow = cst + (i0 - 1) * Mcols;

            // relax free columns + per-lane argmin over this lane's columns
            double bestv = INFINITY;
            int bestj = Mcols + 1;
            for (int j = tid + 1; j <= Mcols; j += 64) {
                if (!used[j]) {
                    double cur = (double)crow[j - 1] - ui0 - v[j];
                    if (cur < minv[j]) { minv[j] = cur; way[j] = j0; }
                    double mv = minv[j];
                    if (mv < bestv) { bestv = mv; bestj = j; } // j ascending -> first wins
                }
            }
            // wave-wide lexicographic (value, index) argmin butterfly
            for (int off = 32; off > 0; off >>= 1) {
                double ov = __shfl_xor(bestv, off);
                int    oj = __shfl_xor(bestj, off);
                if (ov < bestv || (ov == bestv && oj < bestj)) { bestv = ov; bestj = oj; }
            }
            double delta = bestv;
            int j1 = bestj;
            __syncthreads();  // relax writes (minv/way) done before dual update

            for (int j = tid; j <= Mcols; j += 64) {
                if (used[j]) { u[p[j]] += delta; v[j] -= delta; }
                else         { minv[j] -= delta; }
            }
            __syncthreads();

            j0 = j1;
            if (j0 <= Mcols && p[j0] == 0) break;
        }
        // augment along alternating path (short; serial on lane 0; bounded)
        if (tid == 0) {
            int jj = j0;
            for (int step = 0; step < Mcols && jj; ++step) {
                int jn = way[jj]; p[jj] = p[jn]; jj = jn;
            }
        }
        __syncthreads();
    }

    for (int j = tid + 1; j <= Mcols; j += 64) {
        int pi = p[j];
        if (pi > 0) src[b * Tn + (pi - 1)] = j - 1;
    }
}

// ---------------------------------------------------------------------------
// Loss kernel: per-batch partials (weighted CE over queries, L1+GIoU on
// matched pairs). Deterministic tree reduce, doubles, no atomics.
// partials[b*4 + {0:wnll, 1:w, 2:l1, 3:giou}]
// ---------------------------------------------------------------------------
__global__ __launch_bounds__(256) void loss_kernel(
    const float* __restrict__ logits,
    const float* __restrict__ pred_bbox,
    const float* __restrict__ target_bbox,
    const int*   __restrict__ target_labels,
    const int*   __restrict__ src,
    double* __restrict__ partials)
{
    const int b = blockIdx.x;
    const int tid = threadIdx.x;
    __shared__ int cls[Qn];
    for (int q = tid; q < Qn; q += 256) cls[q] = Cn - 1;  // "no object"
    __syncthreads();
    if (tid < Tn) cls[src[b * Tn + tid]] = target_labels[b * Tn + tid];
    __syncthreads();

    double s_wnll = 0.0, s_w = 0.0, s_l1 = 0.0, s_giou = 0.0;

    for (int q = tid; q < Qn; q += 256) {
        float l0 = logits[(b * Qn + q) * Cn + 0];
        float l1 = logits[(b * Qn + q) * Cn + 1];
        float mx = fmaxf(l0, l1);
        float lse = mx + logf(expf(l0 - mx) + expf(l1 - mx));
        int tc = cls[q];
        float lt = (tc == 0) ? l0 : l1;
        float nll = lse - lt;
        float wt = (tc == Cn - 1) ? CLS_SCALE_F : 1.0f;
        s_wnll += (double)(wt * nll);
        s_w    += (double)wt;
    }

    if (tid < Tn) {
        int t = tid;
        int q = src[b * Tn + t];
        const float* pb = pred_bbox + (b * Qn + q) * 4;
        const float* tb = target_bbox + (b * Tn + t) * 4;
        float pcx = pb[0], pcy = pb[1], pw = pb[2], ph = pb[3];
        float tcx = tb[0], tcy = tb[1], tw = tb[2], th = tb[3];
        s_l1 = (double)(fabsf(pcx - tcx) + fabsf(pcy - tcy) +
                        fabsf(pw - tw) + fabsf(ph - th));

        float p0 = pcx - 0.5f * pw, p1 = pcy - 0.5f * ph;
        float p2 = pcx + 0.5f * pw, p3 = pcy + 0.5f * ph;
        float t0 = tcx - 0.5f * tw, t1 = tcy - 0.5f * th;
        float t2 = tcx + 0.5f * tw, t3 = tcy + 0.5f * th;
        float area1 = (p2 - p0) * (p3 - p1);
        float area2 = (t2 - t0) * (t3 - t1);
        float ltx = fmaxf(p0, t0), lty = fmaxf(p1, t1);
        float rbx = fminf(p2, t2), rby = fminf(p3, t3);
        float iw = fmaxf(rbx - ltx, 0.0f), ih = fmaxf(rby - lty, 0.0f);
        float inter = iw * ih;
        float uni = area1 + area2 - inter;
        float iou = inter / uni;
        float ex0 = fminf(p0, t0), ey0 = fminf(p1, t1);
        float ex1 = fmaxf(p2, t2), ey1 = fmaxf(p3, t3);
        float ew = fmaxf(ex1 - ex0, 0.0f), eh = fmaxf(ey1 - ey0, 0.0f);
        float enc = ew * eh;
        float giou = iou - (enc - uni) / enc;
        s_giou = (double)(1.0f - giou);
    }

    // deterministic block tree reduction of 4 doubles
    __shared__ double rbuf[256];
    double vals[4] = { s_wnll, s_w, s_l1, s_giou };
    for (int k = 0; k < 4; ++k) {
        rbuf[tid] = vals[k];
        __syncthreads();
        for (int s = 128; s > 0; s >>= 1) {
            if (tid < s) rbuf[tid] += rbuf[tid + s];
            __syncthreads();
        }
        if (tid == 0) partials[b * 4 + k] = rbuf[0];
        __syncthreads();
    }
}

// ---------------------------------------------------------------------------
// Finalize: combine 32 per-batch partials -> scalar loss
// ---------------------------------------------------------------------------
__global__ void finalize_kernel(const double* __restrict__ partials,
                                float* __restrict__ out)
{
    if (threadIdx.x != 0 || blockIdx.x != 0) return;
    double wnll = 0.0, w = 0.0, l1 = 0.0, gi = 0.0;
    for (int b = 0; b < Bn; ++b) {
        wnll += partials[b * 4 + 0];
        w    += partials[b * 4 + 1];
        l1   += partials[b * 4 + 2];
        gi   += partials[b * 4 + 3];
    }
    double nb = (double)(Bn * Tn);
    double loss = wnll / w + BBOX_SCALE_D * (l1 / nb) + GIOU_SCALE_D * (gi / nb);
    out[0] = (float)loss;
}

// ---------------------------------------------------------------------------
extern "C" void kernel_launch(void* const* d_in, const int* in_sizes, int n_in,
                              void* d_out, int out_size, void* d_ws, size_t ws_size,
                              hipStream_t stream)
{
    const float* logits        = (const float*)d_in[0];
    const float* pred_bbox     = (const float*)d_in[1];
    const float* target_bbox   = (const float*)d_in[2];
    const int*   target_labels = (const int*)d_in[3];
    float* out = (float*)d_out;

    char* ws = (char*)d_ws;
    int* src = (int*)ws;
    size_t off = ((size_t)Bn * Tn * sizeof(int) + 255) & ~(size_t)255;
    double* partials = (double*)(ws + off);

    hipLaunchKernelGGL(lsa_fused_kernel, dim3(Bn), dim3(64), 0, stream,
                       logits, pred_bbox, target_bbox, target_labels, src);
    hipLaunchKernelGGL(loss_kernel, dim3(Bn), dim3(256), 0, stream,
                       logits, pred_bbox, target_bbox, target_labels, src, partials);
    hipLaunchKernelGGL(finalize_kernel, dim3(1), dim3(1), 0, stream, partials, out);
}

// Round 4
// 211.601 us; speedup vs baseline: 1.5132x; 1.5132x over previous
//
#include <hip/hip_runtime.h>
#include <math.h>

#define Bn 32
#define Qn 300
#define Tn 64
#define Cn 2
#define Mcols Qn   /* LSA columns (queries) */
#define Nrows Tn   /* LSA rows (targets)   */
#define NSLOT 5    /* ceil(300/64) columns per lane */

#define CLS_SCALE_F 0.1f
#define BBOX_SCALE_D 5.0
#define GIOU_SCALE_D 2.0

// ---------------------------------------------------------------------------
// Fused kernel: build 64x300 cost tile in LDS, then Jonker-Volgenant LSA.
// One 64-lane wave per batch. Hot relax-loop state (v, minv, u, used) lives
// in registers with a shfl_xor argmin butterfly (no barriers per step);
// p/way bookkeeping stays in LDS with the proven serial lane-0 augmentation.
// FP-exact mirror of reference _lsa: f64 duals, (cost-u)-v order, strict-<
// minv update, first-index argmin tie-break. All loops bounded.
// ---------------------------------------------------------------------------
__global__ __launch_bounds__(64) void lsa_fused_kernel(
    const float* __restrict__ logits,        // [B][Q][C]
    const float* __restrict__ pred_bbox,     // [B][Q][4] cxcywh
    const float* __restrict__ target_bbox,   // [B][T][4] cxcywh
    const int*   __restrict__ target_labels, // [B][T]
    int* __restrict__ src)                   // [B][T] -> matched query
{
    const int b   = blockIdx.x;
    const int tid = threadIdx.x;

    __shared__ float cst[Nrows * Mcols];   // 76800 B, read-only after build
    __shared__ int   p_lds[Mcols + 1];     // row matched to column j (0 = free)
    __shared__ int   way_lds[Mcols + 1];   // parent column in current tree
    __shared__ float tb4[Tn * 4];
    __shared__ int   tlab[Tn];

    // ---- stage targets; init bookkeeping; default src ----
    for (int k = tid; k < Tn * 4; k += 64) tb4[k] = target_bbox[b * Tn * 4 + k];
    for (int k = tid; k < Tn; k += 64)     tlab[k] = target_labels[b * Tn + k];
    for (int j = tid; j <= Mcols; j += 64) { p_lds[j] = 0; way_lds[j] = 0; }
    src[b * Tn + tid] = tid;   // identity fallback; overwritten by emit
    __syncthreads();

    // ---- build cost tile: lane owns query q, loops over 64 targets ----
    for (int qt = 0; qt < NSLOT; ++qt) {
        int q = qt * 64 + tid;
        if (q < Qn) {
            float l0 = logits[(b * Qn + q) * Cn + 0];
            float l1 = logits[(b * Qn + q) * Cn + 1];
            float mx = fmaxf(l0, l1);
            float e0 = expf(l0 - mx), e1 = expf(l1 - mx);
            float den = e0 + e1;
            float pce0 = e0 / den, pce1 = e1 / den;

            const float* pb = pred_bbox + (b * Qn + q) * 4;
            float pcx = pb[0], pcy = pb[1], pw = pb[2], ph = pb[3];
            float p0 = pcx - 0.5f * pw, p1 = pcy - 0.5f * ph;
            float p2 = pcx + 0.5f * pw, p3 = pcy + 0.5f * ph;
            float area1 = (p2 - p0) * (p3 - p1);

            for (int t = 0; t < Tn; ++t) {
                float tcx = tb4[t * 4 + 0], tcy = tb4[t * 4 + 1];
                float tw  = tb4[t * 4 + 2], th  = tb4[t * 4 + 3];
                float cost_bbox = fabsf(pcx - tcx) + fabsf(pcy - tcy) +
                                  fabsf(pw - tw) + fabsf(ph - th);
                float cost_class = (tlab[t] == 0) ? -pce0 : -pce1;

                float t0 = tcx - 0.5f * tw, t1 = tcy - 0.5f * th;
                float t2 = tcx + 0.5f * tw, t3 = tcy + 0.5f * th;
                float area2 = (t2 - t0) * (t3 - t1);
                float ltx = fmaxf(p0, t0), lty = fmaxf(p1, t1);
                float rbx = fminf(p2, t2), rby = fminf(p3, t3);
                float iw = fmaxf(rbx - ltx, 0.0f), ih = fmaxf(rby - lty, 0.0f);
                float inter = iw * ih;
                float uni   = area1 + area2 - inter;
                float iou   = inter / uni;
                float ex0 = fminf(p0, t0), ey0 = fminf(p1, t1);
                float ex1 = fmaxf(p2, t2), ey1 = fmaxf(p3, t3);
                float ew = fmaxf(ex1 - ex0, 0.0f), eh = fmaxf(ey1 - ey0, 0.0f);
                float enc = ew * eh;
                float giou = iou - (enc - uni) / enc;

                cst[t * Mcols + q] = cost_bbox + cost_class - giou;
            }
        }
    }
    __syncthreads();   // cost tile + bookkeeping visible

    // ---- registerized hot state: lane owns columns j-1 = s*64 + tid ----
    double v_[NSLOT], minv_[NSLOT];
    int    pcs_[NSLOT];   // per-Dijkstra snapshot of p for owned columns
    double u_ = 0.0;      // dual of row tid+1
    unsigned usedM;
    #pragma unroll
    for (int s = 0; s < NSLOT; ++s) v_[s] = 0.0;

    const bool valid_[NSLOT] = {
        true, true, true, true, (4 * 64 + tid) < Mcols
    };

    for (int i = 1; i <= Nrows; ++i) {
        // snapshot p (constant during this Dijkstra) + reset minv/used
        #pragma unroll
        for (int s = 0; s < NSLOT; ++s) {
            int j = s * 64 + tid + 1;
            pcs_[s] = valid_[s] ? p_lds[j] : 0;
            minv_[s] = INFINITY;
        }
        usedM = 0;
        bool inTree = (tid == i - 1);   // row i is the tree root
        int i0 = i;
        int j0cur = 0;
        int j1 = 0, pj1 = 0;

        for (int step = 0; step <= Mcols + 1; ++step) {
            double ui0 = __shfl(u_, i0 - 1);
            const float* crow = cst + (i0 - 1) * Mcols;

            // relax free columns; lane-local lex argmin (s asc => j asc)
            double bestv = INFINITY;
            int bestpack = 0x7fffffff;   // (j<<8)|p[j]
            #pragma unroll
            for (int s = 0; s < NSLOT; ++s) {
                if (valid_[s] && !((usedM >> s) & 1u)) {
                    int j = s * 64 + tid + 1;
                    double cur = ((double)crow[j - 1] - ui0) - v_[s];
                    if (cur < minv_[s]) { minv_[s] = cur; way_lds[j] = j0cur; }
                    if (minv_[s] < bestv) {
                        bestv = minv_[s];
                        bestpack = (j << 8) | pcs_[s];
                    }
                }
            }
            // wave-wide lexicographic (value, j) argmin; carries p[j] along
            #pragma unroll
            for (int off = 32; off > 0; off >>= 1) {
                double ov = __shfl_xor(bestv, off);
                int    op = __shfl_xor(bestpack, off);
                if (ov < bestv || (ov == bestv && op < bestpack)) {
                    bestv = ov; bestpack = op;
                }
            }
            double delta = bestv;
            j1  = bestpack >> 8;
            pj1 = bestpack & 0xff;

            // dual update (reference order: u[tree rows], v[used], minv[free])
            if (inTree) u_ += delta;
            #pragma unroll
            for (int s = 0; s < NSLOT; ++s) {
                if ((usedM >> s) & 1u) v_[s] -= delta;
                else if (valid_[s])    minv_[s] -= delta;
            }

            if (pj1 == 0) break;   // reached a free column -> augment

            if (((j1 - 1) & 63) == tid) usedM |= 1u << ((j1 - 1) >> 6);
            if (tid == pj1 - 1) inTree = true;
            i0 = pj1;
            j0cur = j1;
        }

        __syncthreads();   // way_lds stores visible before augment
        if (tid == 0) {
            // serial augmentation along alternating path (round-2-proven)
            int jj = j1;
            for (int st = 0; st < Mcols + 2 && jj != 0; ++st) {
                int jn = way_lds[jj];
                p_lds[jj] = (jn == 0) ? i : p_lds[jn];
                jj = jn;
            }
        }
        __syncthreads();   // p_lds updated before next snapshot
    }

    // ---- emit assignment (guarded) ----
    for (int j = tid + 1; j <= Mcols; j += 64) {
        int pi = p_lds[j];
        if (pi > 0 && pi <= Nrows) src[b * Tn + (pi - 1)] = j - 1;
    }
}

// ---------------------------------------------------------------------------
// Loss kernel: per-batch partials (weighted CE over queries, L1+GIoU on
// matched pairs). Deterministic tree reduce, doubles, no atomics.
// Defensive clamps: bad src degrades to wrong value, never a device fault.
// partials[b*4 + {0:wnll, 1:w, 2:l1, 3:giou}]
// ---------------------------------------------------------------------------
__global__ __launch_bounds__(256) void loss_kernel(
    const float* __restrict__ logits,
    const float* __restrict__ pred_bbox,
    const float* __restrict__ target_bbox,
    const int*   __restrict__ target_labels,
    const int*   __restrict__ src,
    double* __restrict__ partials)
{
    const int b = blockIdx.x;
    const int tid = threadIdx.x;
    __shared__ int cls[Qn];
    for (int q = tid; q < Qn; q += 256) cls[q] = Cn - 1;  // "no object"
    __syncthreads();
    if (tid < Tn) {
        unsigned q = (unsigned)src[b * Tn + tid];
        if (q >= Qn) q = 0;                                // clamp (defensive)
        cls[q] = target_labels[b * Tn + tid];
    }
    __syncthreads();

    double s_wnll = 0.0, s_w = 0.0, s_l1 = 0.0, s_giou = 0.0;

    for (int q = tid; q < Qn; q += 256) {
        float l0 = logits[(b * Qn + q) * Cn + 0];
        float l1 = logits[(b * Qn + q) * Cn + 1];
        float mx = fmaxf(l0, l1);
        float lse = mx + logf(expf(l0 - mx) + expf(l1 - mx));
        int tc = cls[q];
        float lt = (tc == 0) ? l0 : l1;
        float nll = lse - lt;
        float wt = (tc == Cn - 1) ? CLS_SCALE_F : 1.0f;
        s_wnll += (double)(wt * nll);
        s_w    += (double)wt;
    }

    if (tid < Tn) {
        int t = tid;
        unsigned q = (unsigned)src[b * Tn + t];
        if (q >= Qn) q = 0;                                // clamp (defensive)
        const float* pb = pred_bbox + ((size_t)b * Qn + q) * 4;
        const float* tb = target_bbox + ((size_t)b * Tn + t) * 4;
        float pcx = pb[0], pcy = pb[1], pw = pb[2], ph = pb[3];
        float tcx = tb[0], tcy = tb[1], tw = tb[2], th = tb[3];
        s_l1 = (double)(fabsf(pcx - tcx) + fabsf(pcy - tcy) +
                        fabsf(pw - tw) + fabsf(ph - th));

        float p0 = pcx - 0.5f * pw, p1 = pcy - 0.5f * ph;
        float p2 = pcx + 0.5f * pw, p3 = pcy + 0.5f * ph;
        float t0 = tcx - 0.5f * tw, t1 = tcy - 0.5f * th;
        float t2 = tcx + 0.5f * tw, t3 = tcy + 0.5f * th;
        float area1 = (p2 - p0) * (p3 - p1);
        float area2 = (t2 - t0) * (t3 - t1);
        float ltx = fmaxf(p0, t0), lty = fmaxf(p1, t1);
        float rbx = fminf(p2, t2), rby = fminf(p3, t3);
        float iw = fmaxf(rbx - ltx, 0.0f), ih = fmaxf(rby - lty, 0.0f);
        float inter = iw * ih;
        float uni = area1 + area2 - inter;
        float iou = inter / uni;
        float ex0 = fminf(p0, t0), ey0 = fminf(p1, t1);
        float ex1 = fmaxf(p2, t2), ey1 = fmaxf(p3, t3);
        float ew = fmaxf(ex1 - ex0, 0.0f), eh = fmaxf(ey1 - ey0, 0.0f);
        float enc = ew * eh;
        float giou = iou - (enc - uni) / enc;
        s_giou = (double)(1.0f - giou);
    }

    // deterministic block tree reduction of 4 doubles
    __shared__ double rbuf[256];
    double vals[4] = { s_wnll, s_w, s_l1, s_giou };
    for (int k = 0; k < 4; ++k) {
        rbuf[tid] = vals[k];
        __syncthreads();
        for (int s = 128; s > 0; s >>= 1) {
            if (tid < s) rbuf[tid] += rbuf[tid + s];
            __syncthreads();
        }
        if (tid == 0) partials[b * 4 + k] = rbuf[0];
        __syncthreads();
    }
}

// ---------------------------------------------------------------------------
// Finalize: combine 32 per-batch partials -> scalar loss
// ---------------------------------------------------------------------------
__global__ void finalize_kernel(const double* __restrict__ partials,
                                float* __restrict__ out)
{
    if (threadIdx.x != 0 || blockIdx.x != 0) return;
    double wnll = 0.0, w = 0.0, l1 = 0.0, gi = 0.0;
    for (int b = 0; b < Bn; ++b) {
        wnll += partials[b * 4 + 0];
        w    += partials[b * 4 + 1];
        l1   += partials[b * 4 + 2];
        gi   += partials[b * 4 + 3];
    }
    double nb = (double)(Bn * Tn);
    double loss = wnll / w + BBOX_SCALE_D * (l1 / nb) + GIOU_SCALE_D * (gi / nb);
    out[0] = (float)loss;
}

// ---------------------------------------------------------------------------
extern "C" void kernel_launch(void* const* d_in, const int* in_sizes, int n_in,
                              void* d_out, int out_size, void* d_ws, size_t ws_size,
                              hipStream_t stream)
{
    const float* logits        = (const float*)d_in[0];
    const float* pred_bbox     = (const float*)d_in[1];
    const float* target_bbox   = (const float*)d_in[2];
    const int*   target_labels = (const int*)d_in[3];
    float* out = (float*)d_out;

    char* ws = (char*)d_ws;
    int* src = (int*)ws;
    size_t off = ((size_t)Bn * Tn * sizeof(int) + 255) & ~(size_t)255;
    double* partials = (double*)(ws + off);

    hipLaunchKernelGGL(lsa_fused_kernel, dim3(Bn), dim3(64), 0, stream,
                       logits, pred_bbox, target_bbox, target_labels, src);
    hipLaunchKernelGGL(loss_kernel, dim3(Bn), dim3(256), 0, stream,
                       logits, pred_bbox, target_bbox, target_labels, src, partials);
    hipLaunchKernelGGL(finalize_kernel, dim3(1), dim3(1), 0, stream, partials, out);
}

// Round 5
// 139.455 us; speedup vs baseline: 2.2960x; 1.5173x over previous
//
#include <hip/hip_runtime.h>
#include <math.h>

#define Bn 32
#define Qn 300
#define Tn 64
#define Cn 2
#define Mcols Qn   /* LSA columns (queries) */
#define Nrows Tn   /* LSA rows (targets)   */
#define NSLOT 5    /* ceil(300/64) columns per lane */

#define CLS_SCALE_F 0.1f
#define BBOX_SCALE_D 5.0
#define GIOU_SCALE_D 2.0

// ---------------------------------------------------------------------------
// Lexicographic (value, pack) min reduction stages.
// DPP stages (VALU-speed) cover each 16-lane row; shfl stages cross rows.
// Any permutation schedule is valid: lex-min is associative+commutative, so
// full coverage per lane => every lane ends with the global argmin.
// ---------------------------------------------------------------------------
template <int CTRL>
__device__ __forceinline__ void lexmin_dpp(double& bv, int& bp) {
    int lo = __builtin_amdgcn_update_dpp(0, __double2loint(bv), CTRL, 0xF, 0xF, true);
    int hi = __builtin_amdgcn_update_dpp(0, __double2hiint(bv), CTRL, 0xF, 0xF, true);
    int op = __builtin_amdgcn_update_dpp(0, bp,                 CTRL, 0xF, 0xF, true);
    double ov = __hiloint2double(hi, lo);
    if (ov < bv || (ov == bv && op < bp)) { bv = ov; bp = op; }
}
__device__ __forceinline__ void lexmin_shfl(double& bv, int& bp, int off) {
    double ov = __shfl_xor(bv, off);
    int    op = __shfl_xor(bp, off);
    if (ov < bv || (ov == bv && op < bp)) { bv = ov; bp = op; }
}

// ---------------------------------------------------------------------------
// Cost kernel (massively parallel): cost[b][t][q] = L1 - p_class - giou (f32)
// Same op order as the in-wave build => bit-identical tiles either path.
// ---------------------------------------------------------------------------
__global__ __launch_bounds__(256) void cost_kernel(
    const float* __restrict__ logits,        // [B][Q][C]
    const float* __restrict__ pred_bbox,     // [B][Q][4]
    const float* __restrict__ target_bbox,   // [B][T][4]
    const int*   __restrict__ target_labels, // [B][T]
    float* __restrict__ cost)                // [B][T][Q]
{
    int idx = blockIdx.x * blockDim.x + threadIdx.x;
    const int total = Bn * Nrows * Mcols;
    if (idx >= total) return;
    int q = idx % Mcols;
    int t = (idx / Mcols) % Nrows;
    int b = idx / (Mcols * Nrows);

    float l0 = logits[(b * Qn + q) * Cn + 0];
    float l1 = logits[(b * Qn + q) * Cn + 1];
    float mx = fmaxf(l0, l1);
    float e0 = expf(l0 - mx), e1 = expf(l1 - mx);
    float den = e0 + e1;
    float pce0 = e0 / den, pce1 = e1 / den;
    float cost_class = (target_labels[b * Tn + t] == 0) ? -pce0 : -pce1;

    const float* pb = pred_bbox + (b * Qn + q) * 4;
    const float* tb = target_bbox + (b * Tn + t) * 4;
    float pcx = pb[0], pcy = pb[1], pw = pb[2], ph = pb[3];
    float tcx = tb[0], tcy = tb[1], tw = tb[2], th = tb[3];
    float cost_bbox = fabsf(pcx - tcx) + fabsf(pcy - tcy) +
                      fabsf(pw - tw) + fabsf(ph - th);

    float p0 = pcx - 0.5f * pw, p1 = pcy - 0.5f * ph;
    float p2 = pcx + 0.5f * pw, p3 = pcy + 0.5f * ph;
    float t0 = tcx - 0.5f * tw, t1 = tcy - 0.5f * th;
    float t2 = tcx + 0.5f * tw, t3 = tcy + 0.5f * th;
    float area1 = (p2 - p0) * (p3 - p1);
    float area2 = (t2 - t0) * (t3 - t1);
    float ltx = fmaxf(p0, t0), lty = fmaxf(p1, t1);
    float rbx = fminf(p2, t2), rby = fminf(p3, t3);
    float iw = fmaxf(rbx - ltx, 0.0f), ih = fmaxf(rby - lty, 0.0f);
    float inter = iw * ih;
    float uni   = area1 + area2 - inter;
    float iou   = inter / uni;
    float ex0 = fminf(p0, t0), ey0 = fminf(p1, t1);
    float ex1 = fmaxf(p2, t2), ey1 = fmaxf(p3, t3);
    float ew = fmaxf(ex1 - ex0, 0.0f), eh = fmaxf(ey1 - ey0, 0.0f);
    float enc = ew * eh;
    float giou = iou - (enc - uni) / enc;

    cost[((size_t)b * Nrows + t) * Mcols + q] = cost_bbox + cost_class - giou;
}

// ---------------------------------------------------------------------------
// LSA kernel: stage (or build) the 64x300 cost tile in LDS, then JV LSA.
// One 64-lane wave per batch. Hot state (v, minv, u, used, p-snapshot) in
// registers; DPP+shfl lex-argmin butterfly; next-row cost/u prefetched to
// overlap dual-update VALU. p/way bookkeeping in LDS with serial lane-0
// augmentation (round-4-proven). FP-exact mirror of reference _lsa.
// ---------------------------------------------------------------------------
__global__ __launch_bounds__(64) void lsa_kernel(
    const float* __restrict__ logits,
    const float* __restrict__ pred_bbox,
    const float* __restrict__ target_bbox,
    const int*   __restrict__ target_labels,
    const float* __restrict__ gcost,   // [B][T][Q] or unused
    int use_gcost,
    int* __restrict__ src)             // [B][T] -> matched query
{
    const int b   = blockIdx.x;
    const int tid = threadIdx.x;

    __shared__ float cst[Nrows * Mcols];   // 76800 B
    __shared__ int   p_lds[Mcols + 1];
    __shared__ int   way_lds[Mcols + 1];
    __shared__ float tb4[Tn * 4];
    __shared__ int   tlab[Tn];

    for (int j = tid; j <= Mcols; j += 64) { p_lds[j] = 0; way_lds[j] = 0; }
    src[b * Tn + tid] = tid;   // identity fallback; overwritten by emit

    if (use_gcost) {
        // stage precomputed tile: 75 x 1024B direct global->LDS DMA
        const float* gb = gcost + (size_t)b * Nrows * Mcols;
        for (int k = 0; k < 75; ++k) {
            __builtin_amdgcn_global_load_lds(
                (const __attribute__((address_space(1))) void*)(gb + k * 256 + tid * 4),
                (__attribute__((address_space(3))) void*)(cst + k * 256),
                16, 0, 0);
        }
    } else {
        // in-wave build (round-4-proven fallback)
        for (int k = tid; k < Tn * 4; k += 64) tb4[k] = target_bbox[b * Tn * 4 + k];
        for (int k = tid; k < Tn; k += 64)     tlab[k] = target_labels[b * Tn + k];
        __syncthreads();
        for (int qt = 0; qt < NSLOT; ++qt) {
            int q = qt * 64 + tid;
            if (q < Qn) {
                float l0 = logits[(b * Qn + q) * Cn + 0];
                float l1 = logits[(b * Qn + q) * Cn + 1];
                float mx = fmaxf(l0, l1);
                float e0 = expf(l0 - mx), e1 = expf(l1 - mx);
                float den = e0 + e1;
                float pce0 = e0 / den, pce1 = e1 / den;

                const float* pb = pred_bbox + (b * Qn + q) * 4;
                float pcx = pb[0], pcy = pb[1], pw = pb[2], ph = pb[3];
                float p0 = pcx - 0.5f * pw, p1 = pcy - 0.5f * ph;
                float p2 = pcx + 0.5f * pw, p3 = pcy + 0.5f * ph;
                float area1 = (p2 - p0) * (p3 - p1);

                for (int t = 0; t < Tn; ++t) {
                    float tcx = tb4[t * 4 + 0], tcy = tb4[t * 4 + 1];
                    float tw  = tb4[t * 4 + 2], th  = tb4[t * 4 + 3];
                    float cost_bbox = fabsf(pcx - tcx) + fabsf(pcy - tcy) +
                                      fabsf(pw - tw) + fabsf(ph - th);
                    float cost_class = (tlab[t] == 0) ? -pce0 : -pce1;

                    float t0 = tcx - 0.5f * tw, t1 = tcy - 0.5f * th;
                    float t2 = tcx + 0.5f * tw, t3 = tcy + 0.5f * th;
                    float area2 = (t2 - t0) * (t3 - t1);
                    float ltx = fmaxf(p0, t0), lty = fmaxf(p1, t1);
                    float rbx = fminf(p2, t2), rby = fminf(p3, t3);
                    float iw = fmaxf(rbx - ltx, 0.0f), ih = fmaxf(rby - lty, 0.0f);
                    float inter = iw * ih;
                    float uni   = area1 + area2 - inter;
                    float iou   = inter / uni;
                    float ex0 = fminf(p0, t0), ey0 = fminf(p1, t1);
                    float ex1 = fmaxf(p2, t2), ey1 = fmaxf(p3, t3);
                    float ew = fmaxf(ex1 - ex0, 0.0f), eh = fmaxf(ey1 - ey0, 0.0f);
                    float enc = ew * eh;
                    float giou = iou - (enc - uni) / enc;

                    cst[t * Mcols + q] = cost_bbox + cost_class - giou;
                }
            }
        }
    }
    __syncthreads();   // tile + bookkeeping visible (drains vmcnt for DMA)

    // ---- registerized hot state: lane owns columns j-1 = s*64 + tid ----
    double v_[NSLOT], minv_[NSLOT];
    int    pcs_[NSLOT];
    double u_ = 0.0;
    unsigned usedM;
    #pragma unroll
    for (int s = 0; s < NSLOT; ++s) v_[s] = 0.0;

    const bool valid_[NSLOT] = {
        true, true, true, true, (4 * 64 + tid) < Mcols
    };

    for (int i = 1; i <= Nrows; ++i) {
        #pragma unroll
        for (int s = 0; s < NSLOT; ++s) {
            int j = s * 64 + tid + 1;
            pcs_[s] = valid_[s] ? p_lds[j] : 0;
            minv_[s] = INFINITY;
        }
        usedM = 0;
        bool inTree = (tid == i - 1);   // row i is the tree root
        int j0cur = 0;
        int j1 = 0, pj1 = 0;

        // preload row i costs + u[i]
        double ui0 = __shfl(u_, i - 1);
        float c5[NSLOT];
        #pragma unroll
        for (int s = 0; s < NSLOT; ++s) {
            int jj = s * 64 + tid; if (jj >= Mcols) jj = 0;
            c5[s] = cst[(i - 1) * Mcols + jj];
        }

        for (int step = 0; step <= Mcols + 1; ++step) {
            // relax free columns; lane-local lex argmin (s asc => j asc)
            double bestv = INFINITY;
            int bestpack = 0x7fffffff;   // (j<<8)|p[j]
            #pragma unroll
            for (int s = 0; s < NSLOT; ++s) {
                if (valid_[s] && !((usedM >> s) & 1u)) {
                    int j = s * 64 + tid + 1;
                    double cur = ((double)c5[s] - ui0) - v_[s];
                    if (cur < minv_[s]) { minv_[s] = cur; way_lds[j] = j0cur; }
                    if (minv_[s] < bestv) {
                        bestv = minv_[s];
                        bestpack = (j << 8) | pcs_[s];
                    }
                }
            }
            // wave-wide lex (value, j) argmin: 4 DPP stages + 2 shfl stages
            lexmin_dpp<0xB1>(bestv, bestpack);    // quad_perm xor1
            lexmin_dpp<0x4E>(bestv, bestpack);    // quad_perm xor2
            lexmin_dpp<0x124>(bestv, bestpack);   // row_ror:4
            lexmin_dpp<0x128>(bestv, bestpack);   // row_ror:8
            lexmin_shfl(bestv, bestpack, 16);
            lexmin_shfl(bestv, bestpack, 32);

            double delta = bestv;
            j1  = bestpack >> 8;
            pj1 = bestpack & 0xff;

            bool brk = (pj1 == 0);
            if (!brk) {
                // prefetch next row's u and costs; latency overlaps dual update
                // (row pj1 not yet in tree, so its u_ is unchanged this step)
                ui0 = __shfl(u_, pj1 - 1);
                #pragma unroll
                for (int s = 0; s < NSLOT; ++s) {
                    int jj = s * 64 + tid; if (jj >= Mcols) jj = 0;
                    c5[s] = cst[(pj1 - 1) * Mcols + jj];
                }
            }

            // dual update (reference order; usedM excludes j1 this step)
            if (inTree) u_ += delta;
            #pragma unroll
            for (int s = 0; s < NSLOT; ++s) {
                if ((usedM >> s) & 1u) v_[s] -= delta;
                else if (valid_[s])    minv_[s] -= delta;
            }

            if (brk) break;

            if (((j1 - 1) & 63) == tid) usedM |= 1u << ((j1 - 1) >> 6);
            if (tid == pj1 - 1) inTree = true;
            j0cur = j1;
        }

        __syncthreads();   // way_lds stores visible before augment
        if (tid == 0) {
            int jj = j1;
            for (int st = 0; st < Mcols + 2 && jj != 0; ++st) {
                int jn = way_lds[jj];
                p_lds[jj] = (jn == 0) ? i : p_lds[jn];
                jj = jn;
            }
        }
        __syncthreads();   // p_lds updated before next snapshot
    }

    // ---- emit assignment (guarded) ----
    for (int j = tid + 1; j <= Mcols; j += 64) {
        int pi = p_lds[j];
        if (pi > 0 && pi <= Nrows) src[b * Tn + (pi - 1)] = j - 1;
    }
}

// ---------------------------------------------------------------------------
// Loss kernel: per-batch partials. Deterministic tree reduce, doubles.
// Defensive clamps: bad src degrades to wrong value, never a device fault.
// ---------------------------------------------------------------------------
__global__ __launch_bounds__(256) void loss_kernel(
    const float* __restrict__ logits,
    const float* __restrict__ pred_bbox,
    const float* __restrict__ target_bbox,
    const int*   __restrict__ target_labels,
    const int*   __restrict__ src,
    double* __restrict__ partials)
{
    const int b = blockIdx.x;
    const int tid = threadIdx.x;
    __shared__ int cls[Qn];
    for (int q = tid; q < Qn; q += 256) cls[q] = Cn - 1;
    __syncthreads();
    if (tid < Tn) {
        unsigned q = (unsigned)src[b * Tn + tid];
        if (q >= Qn) q = 0;
        cls[q] = target_labels[b * Tn + tid];
    }
    __syncthreads();

    double s_wnll = 0.0, s_w = 0.0, s_l1 = 0.0, s_giou = 0.0;

    for (int q = tid; q < Qn; q += 256) {
        float l0 = logits[(b * Qn + q) * Cn + 0];
        float l1 = logits[(b * Qn + q) * Cn + 1];
        float mx = fmaxf(l0, l1);
        float lse = mx + logf(expf(l0 - mx) + expf(l1 - mx));
        int tc = cls[q];
        float lt = (tc == 0) ? l0 : l1;
        float nll = lse - lt;
        float wt = (tc == Cn - 1) ? CLS_SCALE_F : 1.0f;
        s_wnll += (double)(wt * nll);
        s_w    += (double)wt;
    }

    if (tid < Tn) {
        int t = tid;
        unsigned q = (unsigned)src[b * Tn + t];
        if (q >= Qn) q = 0;
        const float* pb = pred_bbox + ((size_t)b * Qn + q) * 4;
        const float* tb = target_bbox + ((size_t)b * Tn + t) * 4;
        float pcx = pb[0], pcy = pb[1], pw = pb[2], ph = pb[3];
        float tcx = tb[0], tcy = tb[1], tw = tb[2], th = tb[3];
        s_l1 = (double)(fabsf(pcx - tcx) + fabsf(pcy - tcy) +
                        fabsf(pw - tw) + fabsf(ph - th));

        float p0 = pcx - 0.5f * pw, p1 = pcy - 0.5f * ph;
        float p2 = pcx + 0.5f * pw, p3 = pcy + 0.5f * ph;
        float t0 = tcx - 0.5f * tw, t1 = tcy - 0.5f * th;
        float t2 = tcx + 0.5f * tw, t3 = tcy + 0.5f * th;
        float area1 = (p2 - p0) * (p3 - p1);
        float area2 = (t2 - t0) * (t3 - t1);
        float ltx = fmaxf(p0, t0), lty = fmaxf(p1, t1);
        float rbx = fminf(p2, t2), rby = fminf(p3, t3);
        float iw = fmaxf(rbx - ltx, 0.0f), ih = fmaxf(rby - lty, 0.0f);
        float inter = iw * ih;
        float uni = area1 + area2 - inter;
        float iou = inter / uni;
        float ex0 = fminf(p0, t0), ey0 = fminf(p1, t1);
        float ex1 = fmaxf(p2, t2), ey1 = fmaxf(p3, t3);
        float ew = fmaxf(ex1 - ex0, 0.0f), eh = fmaxf(ey1 - ey0, 0.0f);
        float enc = ew * eh;
        float giou = iou - (enc - uni) / enc;
        s_giou = (double)(1.0f - giou);
    }

    __shared__ double rbuf[256];
    double vals[4] = { s_wnll, s_w, s_l1, s_giou };
    for (int k = 0; k < 4; ++k) {
        rbuf[tid] = vals[k];
        __syncthreads();
        for (int s = 128; s > 0; s >>= 1) {
            if (tid < s) rbuf[tid] += rbuf[tid + s];
            __syncthreads();
        }
        if (tid == 0) partials[b * 4 + k] = rbuf[0];
        __syncthreads();
    }
}

// ---------------------------------------------------------------------------
__global__ void finalize_kernel(const double* __restrict__ partials,
                                float* __restrict__ out)
{
    if (threadIdx.x != 0 || blockIdx.x != 0) return;
    double wnll = 0.0, w = 0.0, l1 = 0.0, gi = 0.0;
    for (int b = 0; b < Bn; ++b) {
        wnll += partials[b * 4 + 0];
        w    += partials[b * 4 + 1];
        l1   += partials[b * 4 + 2];
        gi   += partials[b * 4 + 3];
    }
    double nb = (double)(Bn * Tn);
    double loss = wnll / w + BBOX_SCALE_D * (l1 / nb) + GIOU_SCALE_D * (gi / nb);
    out[0] = (float)loss;
}

// ---------------------------------------------------------------------------
extern "C" void kernel_launch(void* const* d_in, const int* in_sizes, int n_in,
                              void* d_out, int out_size, void* d_ws, size_t ws_size,
                              hipStream_t stream)
{
    const float* logits        = (const float*)d_in[0];
    const float* pred_bbox     = (const float*)d_in[1];
    const float* target_bbox   = (const float*)d_in[2];
    const int*   target_labels = (const int*)d_in[3];
    float* out = (float*)d_out;

    char* ws = (char*)d_ws;
    int* src = (int*)ws;                                   // 8192 B
    double* partials = (double*)(ws + 8448);               // 1024 B
    float* gcost = (float*)(ws + 16384);                   // 2457600 B (optional)

    const size_t cost_bytes = (size_t)Bn * Nrows * Mcols * sizeof(float);
    const int use_gcost = (ws_size >= 16384 + cost_bytes) ? 1 : 0;

    if (use_gcost) {
        const int total = Bn * Nrows * Mcols;
        hipLaunchKernelGGL(cost_kernel, dim3((total + 255) / 256), dim3(256), 0, stream,
                           logits, pred_bbox, target_bbox, target_labels, gcost);
    }
    hipLaunchKernelGGL(lsa_kernel, dim3(Bn), dim3(64), 0, stream,
                       logits, pred_bbox, target_bbox, target_labels,
                       gcost, use_gcost, src);
    hipLaunchKernelGGL(loss_kernel, dim3(Bn), dim3(256), 0, stream,
                       logits, pred_bbox, target_bbox, target_labels, src, partials);
    hipLaunchKernelGGL(finalize_kernel, dim3(1), dim3(1), 0, stream, partials, out);
}